// Round 5
// baseline (91.412 us; speedup 1.0000x reference)
//
#include <hip/hip_runtime.h>
#include <hip/hip_bf16.h>
#include <math.h>

#define D_   64
#define HW_  4096
#define N_   16384
#define M_   4096

// ---- fast-path geometry ----
#define BM 64                  // codes per block
#define NSPLIT 16              // n-splits across grid
#define NCHUNK (N_ / NSPLIT)   // 1024 rows per block
#define NTILES (NCHUNK / 128)  // 8 tiles of 128 rows (4 waves x 32)

// ---- fast-path ws layout (floats) ----
#define AZN_OFF 0                      // azn'[16384]
#define AEN_OFF 16384                  // aen'[4096]
#define SUM_OFF 20480                  // sums[4096]
#define ZTB_OFF 24576                  // zT bf16 [16384][64] = 524288 floats
#define EBF_OFF (24576 + 524288)       // e  bf16 [4096][64]  = 131072 floats
#define FAST_WS_FLOATS (EBF_OFF + 131072)

// ---- fallback ws layout (floats) ----
#define FB_AZN 0
#define FB_AEN N_
#define FB_PART (N_ + M_)              // partial[32][4096]

#define L2E 1.4426950408889634f

typedef __attribute__((ext_vector_type(8))) short short8;
typedef __attribute__((ext_vector_type(16))) float floatx16;

#if __has_builtin(__builtin_amdgcn_exp2f)
#define EXP2F(x) __builtin_amdgcn_exp2f(x)
#else
#define EXP2F(x) exp2f(x)
#endif

__device__ __forceinline__ unsigned int bf16_rne(float x) {
    unsigned int u = __float_as_uint(x);
    u += 0x7fffu + ((u >> 16) & 1u);
    return u >> 16;
}

// ======================= FAST PATH =======================

// blocks 0..255: z transpose+scale+norm ; blocks 256..271: e convert+norm+zero sums
__global__ void prep_kernel(const float* __restrict__ z,
                            const float* __restrict__ e,
                            const float* __restrict__ lsp,
                            float* __restrict__ ws) {
    const float ls = lsp[0];
    const float alpha = -0.5f * __expf(-2.f * ls);   // -1/(2 e^{2ls})
    const float anl = alpha * L2E;                   // norm scale (log2 domain)
    const float c2p = -2.f * alpha * L2E;            // z pre-scale
    unsigned short* zTb = (unsigned short*)(ws + ZTB_OFF);
    unsigned short* ebf = (unsigned short*)(ws + EBF_OFF);
    const int blk = blockIdx.x, t = threadIdx.x;

    if (blk < 256) {
        __shared__ float lt[64 * 65];
        const int b = blk >> 6, hw0 = (blk & 63) * 64;
        const int n0 = b * HW_ + hw0;
        const float* zb = z + ((size_t)b * D_) * HW_ + hw0;
#pragma unroll
        for (int i = 0; i < 4; ++i) {
            int idx = t + 256 * i;
            int d = idx >> 4, c = (idx & 15) * 4;
            float4 v = *(const float4*)(zb + (size_t)d * HW_ + c);
            float* p = &lt[d * 65 + c];
            p[0] = v.x; p[1] = v.y; p[2] = v.z; p[3] = v.w;
        }
        __syncthreads();
#pragma unroll
        for (int j = 0; j < 2; ++j) {
            int idx = t + 256 * j;
            int nl = idx >> 3, g = idx & 7;
            float v[8]; float s = 0.f;
#pragma unroll
            for (int jj = 0; jj < 8; ++jj) {
                v[jj] = lt[(8 * g + jj) * 65 + nl];
                s = fmaf(v[jj], v[jj], s);
            }
            s += __shfl_xor(s, 1);
            s += __shfl_xor(s, 2);
            s += __shfl_xor(s, 4);
            uint4 pk;
            pk.x = bf16_rne(v[0] * c2p) | (bf16_rne(v[1] * c2p) << 16);
            pk.y = bf16_rne(v[2] * c2p) | (bf16_rne(v[3] * c2p) << 16);
            pk.z = bf16_rne(v[4] * c2p) | (bf16_rne(v[5] * c2p) << 16);
            pk.w = bf16_rne(v[6] * c2p) | (bf16_rne(v[7] * c2p) << 16);
            *(uint4*)(zTb + (size_t)(n0 + nl) * 64 + 8 * g) = pk;
            if (g == 0) ws[AZN_OFF + n0 + nl] = anl * s;
        }
    } else {
        int m = (blk - 256) * 256 + t;
        const float4* ep = (const float4*)(e + (size_t)m * D_);
        float s = 0.f;
        unsigned int pk[32];
#pragma unroll
        for (int k = 0; k < 16; ++k) {
            float4 v = ep[k];
            s += v.x * v.x + v.y * v.y + v.z * v.z + v.w * v.w;
            pk[2 * k]     = bf16_rne(v.x) | (bf16_rne(v.y) << 16);
            pk[2 * k + 1] = bf16_rne(v.z) | (bf16_rne(v.w) << 16);
        }
        uint4* op = (uint4*)(ebf + (size_t)m * 64);
#pragma unroll
        for (int k = 0; k < 8; ++k)
            op[k] = make_uint4(pk[4 * k], pk[4 * k + 1], pk[4 * k + 2], pk[4 * k + 3]);
        ws[AEN_OFF + m] = anl * s;
        ws[SUM_OFF + m] = 0.f;
    }
}

__global__ __launch_bounds__(256, 3) void main_fast(float* __restrict__ ws) {
    __shared__ float lds_red[BM];
    const unsigned short* zTb = (const unsigned short*)(ws + ZTB_OFF);
    const unsigned short* ebf = (const unsigned short*)(ws + EBF_OFF);
    const float* azn = ws + AZN_OFF;
    const float* aen = ws + AEN_OFF;
    float* sums = ws + SUM_OFF;

    const int m0 = blockIdx.x * BM;
    const int ns = blockIdx.y;
    const int t = threadIdx.x;
    const int lane = t & 63;
    const int w = t >> 6;
    const int rlo = lane & 31;
    const int kh = lane >> 5;

    // B fragments: e rows, register-resident for whole kernel (32 VGPR)
    short8 bf[2][4];
    float aen_r[2];
#pragma unroll
    for (int mt = 0; mt < 2; ++mt) {
        int row = m0 + mt * 32 + rlo;
        aen_r[mt] = aen[row];
#pragma unroll
        for (int ks = 0; ks < 4; ++ks)
            bf[mt][ks] = *(const short8*)(ebf + (size_t)row * 64 + (ks * 2 + kh) * 8);
    }

    float sum[2] = {0.f, 0.f};
    const int nbase = ns * NCHUNK + w * 32;

    // prefetch tile 0
    short8 afc[4];
    float4 aznc[4];
    {
        const int nr = nbase;
#pragma unroll
        for (int ks = 0; ks < 4; ++ks)
            afc[ks] = *(const short8*)(zTb + (size_t)(nr + rlo) * 64 + (ks * 2 + kh) * 8);
        const int r0 = nr + 4 * kh;
#pragma unroll
        for (int rg = 0; rg < 4; ++rg) aznc[rg] = *(const float4*)(azn + r0 + 8 * rg);
    }

#pragma unroll
    for (int tile = 0; tile < NTILES; ++tile) {
        // prefetch next tile while computing current
        short8 afn[4];
        float4 aznn[4];
        if (tile + 1 < NTILES) {
            const int nr = nbase + (tile + 1) * 128;
#pragma unroll
            for (int ks = 0; ks < 4; ++ks)
                afn[ks] = *(const short8*)(zTb + (size_t)(nr + rlo) * 64 + (ks * 2 + kh) * 8);
            const int r0 = nr + 4 * kh;
#pragma unroll
            for (int rg = 0; rg < 4; ++rg) aznn[rg] = *(const float4*)(azn + r0 + 8 * rg);
        }

        float azn_r[16];
#pragma unroll
        for (int rg = 0; rg < 4; ++rg) {
            azn_r[rg * 4 + 0] = aznc[rg].x; azn_r[rg * 4 + 1] = aznc[rg].y;
            azn_r[rg * 4 + 2] = aznc[rg].z; azn_r[rg * 4 + 3] = aznc[rg].w;
        }

        floatx16 acc[2];
#pragma unroll
        for (int mt = 0; mt < 2; ++mt)
#pragma unroll
            for (int r = 0; r < 16; ++r)
                acc[mt][r] = azn_r[r] + aen_r[mt];

#pragma unroll
        for (int ks = 0; ks < 4; ++ks)
#pragma unroll
            for (int mt = 0; mt < 2; ++mt)
                acc[mt] = __builtin_amdgcn_mfma_f32_32x32x16_bf16(
                    afc[ks], bf[mt][ks], acc[mt], 0, 0, 0);

        // epilogue: acc already holds log2-domain exponent -> exp2 + accumulate
#pragma unroll
        for (int mt = 0; mt < 2; ++mt) {
            float s = 0.f;
#pragma unroll
            for (int r = 0; r < 16; ++r) s += EXP2F(acc[mt][r]);
            sum[mt] += s;
        }

#pragma unroll
        for (int ks = 0; ks < 4; ++ks) afc[ks] = afn[ks];
#pragma unroll
        for (int rg = 0; rg < 4; ++rg) aznc[rg] = aznn[rg];
    }

#pragma unroll
    for (int mt = 0; mt < 2; ++mt) sum[mt] += __shfl_down(sum[mt], 32);

    if (t < BM) lds_red[t] = 0.f;
    __syncthreads();
    if (lane < 32) {
#pragma unroll
        for (int mt = 0; mt < 2; ++mt) atomicAdd(&lds_red[mt * 32 + rlo], sum[mt]);
    }
    __syncthreads();
    if (t < BM) atomicAdd(&sums[m0 + t], lds_red[t]);
}

__global__ void finalize_fast(const float* __restrict__ ws,
                              const float* __restrict__ lsp,
                              float* __restrict__ out) {
    __shared__ double red[256];
    const float* sums = ws + SUM_OFF;
    int t = threadIdx.x;
    double local = 0.0;
#pragma unroll
    for (int j = 0; j < 16; ++j) {
        float s = sums[t + 256 * j];
        local += (double)logf(s);
    }
    red[t] = local;
    __syncthreads();
    for (int off = 128; off > 0; off >>= 1) {
        if (t < off) red[t] += red[t + off];
        __syncthreads();
    }
    if (t == 0) {
        double ls = (double)lsp[0];
        double loss = -(red[0] / (double)M_)
                      + 0.5 * (double)D_ * (2.0 * ls - 1.0)
                      + log((double)N_);
        out[0] = (float)loss;
    }
}

// ======================= FALLBACK (R2, proven) =======================

__global__ void norms_kernel(const float* __restrict__ z,
                             const float* __restrict__ e,
                             const float* __restrict__ lsp,
                             float* __restrict__ ws) {
    float ls = lsp[0];
    float alpha = -0.5f * __expf(-2.f * ls);
    int blk = blockIdx.x, t = threadIdx.x;
    if (blk < 64) {
        int n = blk * 256 + t;
        int b = n >> 12, hw = n & 4095;
        const float* zp = z + (size_t)b * D_ * HW_ + hw;
        float s = 0.f;
#pragma unroll
        for (int d = 0; d < D_; ++d) { float v = zp[(size_t)d * HW_]; s = fmaf(v, v, s); }
        ws[FB_AZN + n] = alpha * s;
    } else {
        int m = (blk - 64) * 256 + t;
        const float4* ep = (const float4*)(e + (size_t)m * D_);
        float s = 0.f;
#pragma unroll
        for (int k = 0; k < 16; ++k) {
            float4 v = ep[k];
            s += v.x * v.x + v.y * v.y + v.z * v.z + v.w * v.w;
        }
        ws[FB_AEN + m] = alpha * s;
    }
}

__global__ __launch_bounds__(256, 2) void main_lds(
        const float* __restrict__ z, const float* __restrict__ e,
        const float* __restrict__ lsp, const float* __restrict__ ws,
        float* __restrict__ partial) {
    __shared__ unsigned short lds_a[128 * 64];
    __shared__ unsigned short lds_b[128 * 64];
    __shared__ float lds_azn[128];
    __shared__ float lds_red[128];

    const int m0 = blockIdx.x * 128;
    const int ns = blockIdx.y;
    const int t = threadIdx.x;
    const int lane = t & 63;
    const int w = t >> 6;
    const int rlo = lane & 31;
    const int kh = lane >> 5;

    const float ls = lsp[0];
    const float c2 = __expf(-2.f * ls);

    const float* azn_g = ws + FB_AZN;
    const float* aen_g = ws + FB_AEN;

#pragma unroll
    for (int i = 0; i < 8; ++i) {
        int idx = t + 256 * i;
        int m = idx >> 4, f4 = idx & 15;
        float4 v = *(const float4*)(e + (size_t)(m0 + m) * D_ + f4 * 4);
        unsigned int p0 = bf16_rne(v.x) | (bf16_rne(v.y) << 16);
        unsigned int p1 = bf16_rne(v.z) | (bf16_rne(v.w) << 16);
        int un = m * 8 + ((f4 >> 1) ^ (m & 7));
        unsigned int* dst = (unsigned int*)&lds_b[un * 8 + (f4 & 1) * 4];
        dst[0] = p0; dst[1] = p1;
    }
    float aen_r[4];
#pragma unroll
    for (int mt = 0; mt < 4; ++mt) aen_r[mt] = aen_g[m0 + mt * 32 + rlo];
    __syncthreads();

    short8 bfr[4][4];
#pragma unroll
    for (int mt = 0; mt < 4; ++mt)
#pragma unroll
        for (int ks = 0; ks < 4; ++ks) {
            int row = mt * 32 + rlo;
            int g = ks * 2 + kh;
            bfr[mt][ks] = *(const short8*)&lds_b[(row * 8 + (g ^ (row & 7))) * 8];
        }

    float sum[4] = {0.f, 0.f, 0.f, 0.f};

    for (int tile = 0; tile < 4; ++tile) {
        int n0 = ns * 512 + tile * 128;
        int b   = n0 >> 12;
        int hw0 = n0 & 4095;
        __syncthreads();
#pragma unroll
        for (int i = 0; i < 4; ++i) {
            int idx = t + 256 * i;
            int dp = idx >> 5;
            int c4 = idx & 31;
            int d0 = dp * 2;
            const float* zp = z + ((size_t)(b * D_ + d0)) * HW_ + hw0 + c4 * 4;
            float4 v0 = *(const float4*)zp;
            float4 v1 = *(const float4*)(zp + HW_);
            int g = d0 >> 3;
            float a0[4] = {v0.x, v0.y, v0.z, v0.w};
            float a1[4] = {v1.x, v1.y, v1.z, v1.w};
#pragma unroll
            for (int q = 0; q < 4; ++q) {
                int row = c4 * 4 + q;
                unsigned int pk = bf16_rne(a0[q]) | (bf16_rne(a1[q]) << 16);
                int un = row * 8 + (g ^ (row & 7));
                *(unsigned int*)&lds_a[un * 8 + (d0 & 7)] = pk;
            }
        }
        if (t < 128) lds_azn[t] = azn_g[n0 + t];
        __syncthreads();

        short8 af[4];
        int arow = w * 32 + rlo;
#pragma unroll
        for (int ks = 0; ks < 4; ++ks) {
            int g = ks * 2 + kh;
            af[ks] = *(const short8*)&lds_a[(arow * 8 + (g ^ (arow & 7))) * 8];
        }
        float azn_r[16];
        int r0 = w * 32 + 4 * kh;
#pragma unroll
        for (int rg = 0; rg < 4; ++rg) {
            float4 vv = *(const float4*)&lds_azn[r0 + 8 * rg];
            azn_r[rg * 4 + 0] = vv.x; azn_r[rg * 4 + 1] = vv.y;
            azn_r[rg * 4 + 2] = vv.z; azn_r[rg * 4 + 3] = vv.w;
        }

        floatx16 acc[4] = {};
#pragma unroll
        for (int ks = 0; ks < 4; ++ks)
#pragma unroll
            for (int mt = 0; mt < 4; ++mt)
                acc[mt] = __builtin_amdgcn_mfma_f32_32x32x16_bf16(
                    af[ks], bfr[mt][ks], acc[mt], 0, 0, 0);

#pragma unroll
        for (int mt = 0; mt < 4; ++mt) {
            float s = 0.f;
#pragma unroll
            for (int r = 0; r < 16; ++r) {
                float val = fmaf(acc[mt][r], c2, azn_r[r]) + aen_r[mt];
                s += __expf(val);
            }
            sum[mt] += s;
        }
    }

#pragma unroll
    for (int mt = 0; mt < 4; ++mt) sum[mt] += __shfl_down(sum[mt], 32);

    __syncthreads();
    if (t < 128) lds_red[t] = 0.f;
    __syncthreads();
    if (lane < 32) {
#pragma unroll
        for (int mt = 0; mt < 4; ++mt) atomicAdd(&lds_red[mt * 32 + rlo], sum[mt]);
    }
    __syncthreads();
    if (t < 128) partial[(size_t)ns * M_ + m0 + t] = lds_red[t];
}

__global__ void finalize_part(const float* __restrict__ partial,
                              const float* __restrict__ lsp,
                              float* __restrict__ out) {
    __shared__ double red[256];
    int t = threadIdx.x;
    double local = 0.0;
#pragma unroll
    for (int j = 0; j < 16; ++j) {
        int m = t + 256 * j;
        float s = 0.f;
#pragma unroll
        for (int k = 0; k < 32; ++k) s += partial[(size_t)k * M_ + m];
        local += (double)logf(s);
    }
    red[t] = local;
    __syncthreads();
    for (int off = 128; off > 0; off >>= 1) {
        if (t < off) red[t] += red[t + off];
        __syncthreads();
    }
    if (t == 0) {
        double ls = (double)lsp[0];
        double loss = -(red[0] / (double)M_)
                      + 0.5 * (double)D_ * (2.0 * ls - 1.0)
                      + log((double)N_);
        out[0] = (float)loss;
    }
}

extern "C" void kernel_launch(void* const* d_in, const int* in_sizes, int n_in,
                              void* d_out, int out_size, void* d_ws, size_t ws_size,
                              hipStream_t stream) {
    const float* z   = (const float*)d_in[0];
    const float* e   = (const float*)d_in[1];
    const float* lsp = (const float*)d_in[2];
    float* ws  = (float*)d_ws;
    float* out = (float*)d_out;

    if (ws_size >= (size_t)FAST_WS_FLOATS * sizeof(float)) {
        hipLaunchKernelGGL(prep_kernel, dim3(272), dim3(256), 0, stream, z, e, lsp, ws);
        hipLaunchKernelGGL(main_fast, dim3(M_ / BM, NSPLIT), dim3(256), 0, stream, ws);
        hipLaunchKernelGGL(finalize_fast, dim3(1), dim3(256), 0, stream, ws, lsp, out);
    } else {
        hipLaunchKernelGGL(norms_kernel, dim3(80), dim3(256), 0, stream, z, e, lsp, ws);
        hipLaunchKernelGGL(main_lds, dim3(32, 32), dim3(256), 0, stream,
                           z, e, lsp, ws, ws + FB_PART);
        hipLaunchKernelGGL(finalize_part, dim3(1), dim3(256), 0, stream,
                           ws + FB_PART, lsp, out);
    }
}